// Round 9
// baseline (314.542 us; speedup 1.0000x reference)
//
#include <hip/hip_runtime.h>

// RandHashProj: out[b,o] = sum_{i: sel[i]==o} sign[i] * x[b,i]
// B=32, N=1e6, OUT_FEAT=1024.
// R5 post-mortem: 167us accum @ 8.5% HBM, VALUBusy 1.4%, VGPR=16 -> CAS-loop
// float atomics + register-starved serial loads. Fixes:
//  - unsafeAtomicAdd -> native ds_add_f32 (fire-and-forget, no lgkmcnt chain)
//  - per-wave row ownership: 1 x4-load + 4 atomics per iter, sel/sign read 1x/block
//  - LDS row regions padded to stride 1028 (4*row+sel mod 32 -> distinct banks)
//  - reduce: contiguous 1KB/wave float4 streaming + unsafe global atomics

constexpr int OUT_FEAT   = 1024;
constexpr int BGRP       = 8;                  // batch rows per block
constexpr int NGRP       = 4;                  // 32 / BGRP
constexpr int NCHUNK     = 256;                // column chunks
constexpr int BLK1       = 512;
constexpr int REG_STRIDE = 1028;               // pad: 1028 % 32 = 4 -> row r shifts banks by 4r
constexpr int ACC_ELEMS  = BGRP * OUT_FEAT;    // 8192 floats (ws layout, unpadded)
constexpr int B_TOT      = 32;
constexpr int QS         = 16;                 // reduce chunk-splits

__global__ __launch_bounds__(BLK1) void rhp_accum(
    const float* __restrict__ x, const int* __restrict__ sel,
    const float* __restrict__ sgn, float* __restrict__ ws,
    float* __restrict__ out_atomic, int N)
{
    __shared__ float acc[BGRP * REG_STRIDE];   // 32,896 B -> 4 blocks/CU
    const int tid = threadIdx.x;
    for (int j = tid; j < BGRP * REG_STRIDE; j += BLK1) acc[j] = 0.0f;
    __syncthreads();

    const int g     = blockIdx.x;              // batch group 0..3
    const int chunk = blockIdx.y;              // column chunk 0..255
    const int C4    = N >> 2;                  // float4 columns
    const int per   = (C4 + NCHUNK - 1) / NCHUNK;
    const int start = chunk * per;
    const int end   = min(start + per, C4);

    const int row = tid & (BGRP - 1);          // this thread's batch row
    const int lc  = tid >> 3;                  // column slot 0..63
    float* __restrict__ myacc = acc + row * REG_STRIDE;
    const float4* __restrict__ xrow = (const float4*)x + (size_t)(g * BGRP + row) * C4;
    const int4*   __restrict__ sel4 = (const int4*)sel;
    const float4* __restrict__ sg4  = (const float4*)sgn;

    #pragma unroll 4
    for (int c = start + lc; c < end; c += 64) {
        const int4   s  = sel4[c];
        const float4 sg = sg4[c];
        const float4 xv = xrow[c];
        unsafeAtomicAdd(&myacc[s.x], xv.x * sg.x);   // ds_add_f32, no return
        unsafeAtomicAdd(&myacc[s.y], xv.y * sg.y);
        unsafeAtomicAdd(&myacc[s.z], xv.z * sg.z);
        unsafeAtomicAdd(&myacc[s.w], xv.w * sg.w);
    }
    __syncthreads();

    if (ws) {
        // coalesced float4 flush: ws[g][chunk][bl][o] (unpadded)
        float4* __restrict__ dst = (float4*)ws + (size_t)(g * NCHUNK + chunk) * (ACC_ELEMS / 4);
        for (int j4 = tid; j4 < ACC_ELEMS / 4; j4 += BLK1) {
            const int bl = j4 >> 8, o4 = j4 & 255;
            dst[j4] = *(const float4*)&acc[bl * REG_STRIDE + o4 * 4];
        }
    } else {
        // fallback: direct global atomic flush (out pre-zeroed)
        for (int j = tid; j < ACC_ELEMS; j += BLK1) {
            const int bl = j >> 10, o = j & (OUT_FEAT - 1);
            unsafeAtomicAdd(&out_atomic[(size_t)(g * BGRP + bl) * OUT_FEAT + o],
                            acc[bl * REG_STRIDE + o]);
        }
    }
}

// ws: [g:4][chunk:256][bl:8][o:1024] f32. Block (row, q) sums 16 chunks for one
// batch row; wave reads 1KB contiguous per iteration.
__global__ __launch_bounds__(256) void rhp_reduce(
    const float* __restrict__ ws, float* __restrict__ out)
{
    const int rowb = blockIdx.x;               // 0..31
    const int q    = blockIdx.y;               // 0..QS-1
    const int g  = rowb >> 3;
    const int bl = rowb & (BGRP - 1);
    const int o4 = threadIdx.x;                // 0..255 (float4 index in the row)

    const float4* __restrict__ src = (const float4*)ws;
    float4 a = make_float4(0.f, 0.f, 0.f, 0.f);
    #pragma unroll 4
    for (int ch = q * (NCHUNK / QS); ch < (q + 1) * (NCHUNK / QS); ++ch) {
        const float4 v = src[(((size_t)g * NCHUNK + ch) * BGRP + bl) * 256 + o4];
        a.x += v.x; a.y += v.y; a.z += v.z; a.w += v.w;
    }
    float* op = out + (size_t)rowb * OUT_FEAT + o4 * 4;
    unsafeAtomicAdd(op + 0, a.x);
    unsafeAtomicAdd(op + 1, a.y);
    unsafeAtomicAdd(op + 2, a.z);
    unsafeAtomicAdd(op + 3, a.w);
}

extern "C" void kernel_launch(void* const* d_in, const int* in_sizes, int n_in,
                              void* d_out, int out_size, void* d_ws, size_t ws_size,
                              hipStream_t stream)
{
    const float* x   = (const float*)d_in[0];
    const int*   sel = (const int*)d_in[1];
    const float* sgn = (const float*)d_in[2];
    float*       out = (float*)d_out;
    const int    N   = in_sizes[1];            // 1,000,000

    const size_t need = (size_t)NGRP * NCHUNK * ACC_ELEMS * sizeof(float); // 32 MB

    // out is re-poisoned to 0xAA before every timed launch — zero it.
    hipMemsetAsync(d_out, 0, (size_t)out_size * sizeof(float), stream);

    if (ws_size >= need) {
        float* ws = (float*)d_ws;
        rhp_accum<<<dim3(NGRP, NCHUNK), BLK1, 0, stream>>>(x, sel, sgn, ws, nullptr, N);
        rhp_reduce<<<dim3(B_TOT, QS), 256, 0, stream>>>(ws, out);
    } else {
        rhp_accum<<<dim3(NGRP, NCHUNK), BLK1, 0, stream>>>(x, sel, sgn, nullptr, out, N);
    }
}

// Round 10
// 310.421 us; speedup vs baseline: 1.0133x; 1.0133x over previous
//
#include <hip/hip_runtime.h>

// RandHashProj: out[b,o] = sum_{i: sel[i]==o} sign[i] * x[b,i]
// B=32, N=1e6, OUT_FEAT=1024.
// R9 post-mortem: R5 and R9 accums IDENTICAL (166us, VGPR=16, VALUBusy 2%)
// despite different inner loops -> LDS atomicAdd was already ds_add_f32;
// compiler serializes loads (no ILP); reduce dispatch costs ~145us for 32MB.
// R10 experiment: ONE fused kernel (no ws, no 2nd dispatch), hand software-
// pipelined loads (prefetch next iter before atomics), wave-uniform row
// (perfect 1KB/instr x coalescing), direct global-atomic flush to out.

constexpr int OUT_FEAT = 1024;
constexpr int BGRP   = 8;                  // batch rows per block
constexpr int NGRP   = 4;                  // 32 / BGRP
constexpr int NCHUNK = 125;                // 250000 f4-cols / 125 = 2000 exact
constexpr int BLK    = 1024;
constexpr int LC     = BLK / BGRP;         // 128 column slots
constexpr int STRIDE = 1028;               // bank-spread pad (1028 % 32 = 4)

__global__ __launch_bounds__(BLK) void rhp_fused(
    const float* __restrict__ x, const int* __restrict__ sel,
    const float* __restrict__ sgn, float* __restrict__ out, int N)
{
    __shared__ float acc[BGRP * STRIDE];   // 32,896 B -> 2 blocks/CU, 32 waves
    const int tid = threadIdx.x;
    for (int j = tid; j < BGRP * STRIDE; j += BLK) acc[j] = 0.0f;
    __syncthreads();

    const int g     = blockIdx.x;          // batch group 0..3
    const int chunk = blockIdx.y;          // column chunk 0..124
    const int C4    = N >> 2;              // 250000 float4 columns
    const int per   = (C4 + NCHUNK - 1) / NCHUNK;   // 2000
    const int start = chunk * per;
    const int end   = min(start + per, C4);

    const int row = tid >> 7;              // wave-uniform: whole wave = one row
    const int lc  = tid & (LC - 1);        // column slot 0..127
    float* __restrict__ myacc = acc + row * STRIDE;
    const float4* __restrict__ xrow = (const float4*)x + (size_t)(g * BGRP + row) * C4;
    const int4*   __restrict__ sel4 = (const int4*)sel;
    const float4* __restrict__ sg4  = (const float4*)sgn;

    // software pipeline: issue next iteration's 3 loads before this
    // iteration's atomics so vmcnt overlap is forced at source level.
    int c = start + lc;
    int4   s  = make_int4(0, 0, 0, 0);
    float4 sg = make_float4(0.f, 0.f, 0.f, 0.f);
    float4 xv = sg;
    if (c < end) { s = sel4[c]; sg = sg4[c]; xv = xrow[c]; }
    while (c < end) {
        const int cn = c + LC;
        int4   s2  = make_int4(0, 0, 0, 0);
        float4 sg2 = make_float4(0.f, 0.f, 0.f, 0.f);
        float4 xv2 = sg2;
        if (cn < end) { s2 = sel4[cn]; sg2 = sg4[cn]; xv2 = xrow[cn]; }
        unsafeAtomicAdd(&myacc[s.x], xv.x * sg.x);   // ds_add_f32
        unsafeAtomicAdd(&myacc[s.y], xv.y * sg.y);
        unsafeAtomicAdd(&myacc[s.z], xv.z * sg.z);
        unsafeAtomicAdd(&myacc[s.w], xv.w * sg.w);
        c = cn; s = s2; sg = sg2; xv = xv2;
    }
    __syncthreads();

    // direct flush to out (pre-zeroed): 8192 lane-ops/block, coalesced
    // 256B segments, native global_atomic_add_f32 (device scope).
    for (int j = tid; j < BGRP * OUT_FEAT; j += BLK) {
        const int bl = j >> 10, o = j & (OUT_FEAT - 1);
        unsafeAtomicAdd(&out[(size_t)(g * BGRP + bl) * OUT_FEAT + o],
                        acc[bl * STRIDE + o]);
    }
}

extern "C" void kernel_launch(void* const* d_in, const int* in_sizes, int n_in,
                              void* d_out, int out_size, void* d_ws, size_t ws_size,
                              hipStream_t stream)
{
    const float* x   = (const float*)d_in[0];
    const int*   sel = (const int*)d_in[1];
    const float* sgn = (const float*)d_in[2];
    float*       out = (float*)d_out;
    const int    N   = in_sizes[1];        // 1,000,000

    // out is re-poisoned to 0xAA before every timed launch — zero it.
    hipMemsetAsync(d_out, 0, (size_t)out_size * sizeof(float), stream);

    rhp_fused<<<dim3(NGRP, NCHUNK), BLK, 0, stream>>>(x, sel, sgn, out, N);
}

// Round 15
// 231.693 us; speedup vs baseline: 1.3576x; 1.3398x over previous
//
#include <hip/hip_runtime.h>

// RandHashProj: out[b,o] = sum_{i: sel[i]==o} sign[i] * x[b,i]
// B=32, N=1e6, OUT_FEAT=1024.
// R13 post-mortem: CSR v1 failed absmax 1.5e6. Prime suspect: 74KB static LDS
// in gather exceeding the 64KB static-shared launch limit -> silent launch
// failure -> reduce summed stale ws garbage. This version: gather LDS 44.3KB
// (WSZ 2048, 4 rows, u32 entries), build 1 int4/thread, defensive walk clamps.
// No atomics in the hot path (R10 established the ~170us LDS-atomic wall).

constexpr int OUT_FEAT = 1024;
constexpr int B_TOT    = 32;
constexpr int WSZ      = 2048;               // columns per window
constexpr int NW       = 489;                // ceil(1e6/2048)
constexpr int BLK_B    = 512;                // build block: 1 int4/thread
constexpr int BLK_G    = 512;                // gather block (8 waves)
constexpr int WPB      = 4;                  // windows per gather block
constexpr int NWB      = 123;                // ceil(NW/WPB)
constexpr int NQ       = 8;                  // batch quads (32/4)
constexpr int TAB_STRIDE = 1032;             // u32 units per window table

constexpr size_t ENT_OFF = 0;                                  // u32[NW*2048]
constexpr size_t TAB_OFF = 4u * 1024 * 1024;                   // u32[NW*1032]
constexpr size_t PAR_OFF = 8u * 1024 * 1024;                   // f32[NWB*32*1024]
constexpr size_t WS_NEED = PAR_OFF + (size_t)NWB * B_TOT * OUT_FEAT * 4;

// ---------------- Phase 1: per-window CSR build ----------------
__global__ __launch_bounds__(BLK_B) void rhp_build(
    const int* __restrict__ sel, const float* __restrict__ sgn,
    unsigned int* __restrict__ entg, unsigned int* __restrict__ tabg, int N)
{
    __shared__ unsigned int hist[OUT_FEAT];    // 4KB
    __shared__ unsigned int cursor[OUT_FEAT];  // 4KB
    __shared__ unsigned int ent[WSZ];          // 8KB
    __shared__ unsigned int wsum[8];

    const int w = blockIdx.x;
    const int t = threadIdx.x;
    const int c4 = w * (WSZ / 4) + t;          // global int4 index

    hist[t] = 0u; hist[t + 512] = 0u;
    __syncthreads();

    const bool ok = (4 * c4 < N);              // N%4==0: all-or-nothing
    int4 sv; float4 gv;
    if (ok) {
        sv = ((const int4*)sel)[c4];
        gv = ((const float4*)sgn)[c4];
        atomicAdd(&hist[sv.x], 1u);
        atomicAdd(&hist[sv.y], 1u);
        atomicAdd(&hist[sv.z], 1u);
        atomicAdd(&hist[sv.w], 1u);
    }
    __syncthreads();

    // prefix sum over 1024 bins, 2 per thread, 8 waves
    const unsigned h0 = hist[2*t], h1 = hist[2*t + 1];
    const unsigned s  = h0 + h1;
    unsigned inc = s;
    #pragma unroll
    for (int d = 1; d < 64; d <<= 1) {
        const unsigned v = __shfl_up(inc, d, 64);
        if ((t & 63) >= d) inc += v;
    }
    const int wv = t >> 6;
    if ((t & 63) == 63) wsum[wv] = inc;
    __syncthreads();
    unsigned woff = 0;
    for (int i = 0; i < wv; ++i) woff += wsum[i];
    const unsigned excl = woff + inc - s;

    unsigned int* __restrict__ tab = tabg + (size_t)w * TAB_STRIDE;
    cursor[2*t]     = excl;       tab[2*t]     = excl;
    cursor[2*t + 1] = excl + h0;  tab[2*t + 1] = excl + h0;
    if (t == BLK_B - 1) tab[OUT_FEAT] = woff + inc;   // total entries
    __syncthreads();

    // scatter entries: (local col 11b | sign bit 0x8000)
    if (ok) {
        const unsigned lc = 4u * (unsigned)t;
        unsigned p;
        p = atomicAdd(&cursor[sv.x], 1u); ent[p] = (lc    ) | (gv.x < 0.f ? 0x8000u : 0u);
        p = atomicAdd(&cursor[sv.y], 1u); ent[p] = (lc + 1) | (gv.y < 0.f ? 0x8000u : 0u);
        p = atomicAdd(&cursor[sv.z], 1u); ent[p] = (lc + 2) | (gv.z < 0.f ? 0x8000u : 0u);
        p = atomicAdd(&cursor[sv.w], 1u); ent[p] = (lc + 3) | (gv.w < 0.f ? 0x8000u : 0u);
    }
    __syncthreads();

    unsigned int* __restrict__ eo = entg + (size_t)w * WSZ;
    #pragma unroll
    for (int k = 0; k < WSZ / BLK_B; ++k) eo[t + k * BLK_B] = ent[t + k * BLK_B];
}

// ---------------- Phase 2: gather (no atomics) ----------------
__global__ __launch_bounds__(BLK_G) void rhp_gather(
    const float* __restrict__ x,
    const unsigned int* __restrict__ entg,
    const unsigned int* __restrict__ tabg,
    float* __restrict__ par, int N)
{
    __shared__ float        xq[WSZ * 4];       // [col][4 rows], 32KB
    __shared__ unsigned int ent[WSZ];          // 8KB
    __shared__ unsigned int tab[OUT_FEAT + 1]; // 4.1KB   -> total 44.3KB

    const int bq = blockIdx.x;                 // 0..7  (batch quad)
    const int wb = blockIdx.y;                 // 0..122 (window bundle)
    const int t  = threadIdx.x;
    const int r0 = bq * 4;

    float acc0[4] = {0.f, 0.f, 0.f, 0.f};      // bucket o = t
    float acc1[4] = {0.f, 0.f, 0.f, 0.f};      // bucket o = t + 512

    for (int i = 0; i < WPB; ++i) {
        const int w = wb * WPB + i;
        if (w >= NW) break;                    // block-uniform
        const int base = w * WSZ;

        // stage x rows r0..r0+3 interleaved: xq[col*4 + r]
        #pragma unroll
        for (int it = 0; it < WSZ / BLK_G; ++it) {   // 4 iters
            const int col = t + it * BLK_G;
            const int gc  = base + col;
            float4 v = make_float4(0.f, 0.f, 0.f, 0.f);
            if (gc < N) {
                v.x = x[(size_t)(r0 + 0) * N + gc];
                v.y = x[(size_t)(r0 + 1) * N + gc];
                v.z = x[(size_t)(r0 + 2) * N + gc];
                v.w = x[(size_t)(r0 + 3) * N + gc];
            }
            *(float4*)&xq[col * 4] = v;
        }
        // stage entries (2048 u32)
        const unsigned int* __restrict__ es = entg + (size_t)w * WSZ;
        #pragma unroll
        for (int k = 0; k < WSZ / BLK_G; ++k) ent[t + k * BLK_G] = es[t + k * BLK_G];
        // stage table (1025 u32)
        const unsigned int* __restrict__ ts = tabg + (size_t)w * TAB_STRIDE;
        for (int j = t; j < OUT_FEAT + 1; j += BLK_G) tab[j] = ts[j];
        __syncthreads();

        // walk bucket o = t
        {
            unsigned j0 = tab[t], j1 = tab[t + 1];
            if (j1 > (unsigned)WSZ) j1 = WSZ;          // defensive no-op
            for (unsigned j = j0; j < j1; ++j) {
                const unsigned e = ent[j];
                const float4 v = *(const float4*)&xq[(e & 0x7FFu) * 4];
                const float sf = (e & 0x8000u) ? -1.f : 1.f;
                acc0[0] += sf * v.x; acc0[1] += sf * v.y;
                acc0[2] += sf * v.z; acc0[3] += sf * v.w;
            }
        }
        // walk bucket o = t + 512
        {
            unsigned j0 = tab[t + 512], j1 = tab[t + 513];
            if (j1 > (unsigned)WSZ) j1 = WSZ;
            for (unsigned j = j0; j < j1; ++j) {
                const unsigned e = ent[j];
                const float4 v = *(const float4*)&xq[(e & 0x7FFu) * 4];
                const float sf = (e & 0x8000u) ? -1.f : 1.f;
                acc1[0] += sf * v.x; acc1[1] += sf * v.y;
                acc1[2] += sf * v.z; acc1[3] += sf * v.w;
            }
        }
        __syncthreads();                       // before LDS reuse
    }

    // partials: par[(wb*32 + row)*1024 + o]
    #pragma unroll
    for (int r = 0; r < 4; ++r)
        par[((size_t)wb * B_TOT + r0 + r) * OUT_FEAT + t] = acc0[r];
    #pragma unroll
    for (int r = 0; r < 4; ++r)
        par[((size_t)wb * B_TOT + r0 + r) * OUT_FEAT + t + 512] = acc1[r];
}

// ---------------- Phase 3: reduce partials ----------------
__global__ __launch_bounds__(256) void rhp_reduce(
    const float* __restrict__ par, float* __restrict__ out)
{
    const int idx = blockIdx.x * 256 + threadIdx.x;   // 0..32767
    float a = 0.f;
    #pragma unroll 4
    for (int wb = 0; wb < NWB; ++wb)
        a += par[(size_t)wb * (B_TOT * OUT_FEAT) + idx];
    out[idx] = a;
}

// ---------------- Fallback (ws too small): R10 fused scatter (passed) -------
constexpr int FB_BGRP = 8, FB_NGRP = 4, FB_NCHUNK = 125, FB_BLK = 1024;
constexpr int FB_LC = FB_BLK / FB_BGRP, FB_STRIDE = 1028;

__global__ __launch_bounds__(FB_BLK) void rhp_fused(
    const float* __restrict__ x, const int* __restrict__ sel,
    const float* __restrict__ sgn, float* __restrict__ out, int N)
{
    __shared__ float acc[FB_BGRP * FB_STRIDE];
    const int tid = threadIdx.x;
    for (int j = tid; j < FB_BGRP * FB_STRIDE; j += FB_BLK) acc[j] = 0.0f;
    __syncthreads();
    const int g = blockIdx.x, chunk = blockIdx.y;
    const int C4 = N >> 2;
    const int per = (C4 + FB_NCHUNK - 1) / FB_NCHUNK;
    const int start = chunk * per, end = min(start + per, C4);
    const int row = tid >> 7, lc = tid & (FB_LC - 1);
    float* myacc = acc + row * FB_STRIDE;
    const float4* xrow = (const float4*)x + (size_t)(g * FB_BGRP + row) * C4;
    const int4* sel4 = (const int4*)sel;
    const float4* sg4 = (const float4*)sgn;
    for (int c = start + lc; c < end; c += FB_LC) {
        const int4 s = sel4[c]; const float4 sg = sg4[c]; const float4 xv = xrow[c];
        unsafeAtomicAdd(&myacc[s.x], xv.x * sg.x);
        unsafeAtomicAdd(&myacc[s.y], xv.y * sg.y);
        unsafeAtomicAdd(&myacc[s.z], xv.z * sg.z);
        unsafeAtomicAdd(&myacc[s.w], xv.w * sg.w);
    }
    __syncthreads();
    for (int j = tid; j < FB_BGRP * OUT_FEAT; j += FB_BLK) {
        const int bl = j >> 10, o = j & (OUT_FEAT - 1);
        unsafeAtomicAdd(&out[(size_t)(g * FB_BGRP + bl) * OUT_FEAT + o],
                        acc[bl * FB_STRIDE + o]);
    }
}

extern "C" void kernel_launch(void* const* d_in, const int* in_sizes, int n_in,
                              void* d_out, int out_size, void* d_ws, size_t ws_size,
                              hipStream_t stream)
{
    const float* x   = (const float*)d_in[0];
    const int*   sel = (const int*)d_in[1];
    const float* sgn = (const float*)d_in[2];
    float*       out = (float*)d_out;
    const int    N   = in_sizes[1];            // 1,000,000

    if (ws_size >= WS_NEED) {
        unsigned int* entg = (unsigned int*)((char*)d_ws + ENT_OFF);
        unsigned int* tabg = (unsigned int*)((char*)d_ws + TAB_OFF);
        float*        par  = (float*)((char*)d_ws + PAR_OFF);
        rhp_build <<<NW, BLK_B, 0, stream>>>(sel, sgn, entg, tabg, N);
        rhp_gather<<<dim3(NQ, NWB), BLK_G, 0, stream>>>(x, entg, tabg, par, N);
        rhp_reduce<<<(B_TOT * OUT_FEAT) / 256, 256, 0, stream>>>(par, out);
    } else {
        hipMemsetAsync(d_out, 0, (size_t)out_size * sizeof(float), stream);
        rhp_fused<<<dim3(FB_NGRP, FB_NCHUNK), FB_BLK, 0, stream>>>(x, sel, sgn, out, N);
    }
}